// Round 8
// baseline (42.178 us; speedup 1.0000x reference)
//
#include <hip/hip_runtime.h>

// FastGuidedFilter, fully fused, 16 highres rows per block (1536 blocks = 6/CU).
// Identical to round-7 structure except phase 5 uses a DEPTH-8 prefetch ring:
// load->use distance ~8 iters (~960 cy) covers HBM latency while keeping the
// read and write streams interleaved (copy-ubench-like mixed streaming).
// Phases (5 barriers per 16 hr rows):
//  1. stage 10 lowres rows of x,y into LDS (zero outside image)
//  2. vertical 5-tap rolling window sums -> f4{sx,sy,sxy,sxx} col-sums for
//     6 A/b rows into zero-padded LDS (aliases staging)
//  3. horizontal 5 x ds_read_b128 taps -> stats -> A,b (6 rows) in registers
//  4. A,b -> LDS f2 (aliases col-sums); read back only columns {t-1,t,t+1}
//  5. per hr row (depth-8 ring, fully unrolled): y-combine 3 columns,
//     2-way select x-interp, out = A*x_hr + b, nontemporal store.

typedef float f4 __attribute__((ext_vector_type(4)));
typedef float f2 __attribute__((ext_vector_type(2)));

constexpr int H_LR = 256, W_LR = 256;
constexpr int H_HR = 1024, W_HR = 1024;
constexpr int NC   = 24;       // 8 * 3
constexpr int RAD  = 2;        // kernel_size 5
constexpr int RPB  = 16;       // highres rows per block
constexpr int NAB  = 6;        // A/b rows a 16-row group can touch
constexpr int NST  = 10;       // staged lowres rows (NAB + 2*RAD)
constexpr int CS_W = W_LR + 4; // zero-padded col-sum width
constexpr int PD   = 8;        // phase-5 prefetch depth

constexpr int LDS_BYTES = NAB * CS_W * 4 * 4;  // 24960 (largest aliased region)

__global__ void __launch_bounds__(256) fgf_fused(const float* __restrict__ xlr,
                                                 const float* __restrict__ ylr,
                                                 const float* __restrict__ xhr,
                                                 float* __restrict__ out) {
    __shared__ __align__(16) char lds[LDS_BYTES];
    auto sx = reinterpret_cast<float(*)[W_LR]>(lds);                   // [10][256]
    auto sy = reinterpret_cast<float(*)[W_LR]>(lds + NST * W_LR * 4);  // [10][256]
    auto cs = reinterpret_cast<float(*)[CS_W][4]>(lds);                // [6][260][4]
    auto ab = reinterpret_cast<f2(*)[W_LR]>(lds);                      // [6][256] f2

    const int c  = blockIdx.y;
    const int i0 = blockIdx.x * RPB;
    const int t  = (int)threadIdx.x;
    const float scale = (float)(H_LR - 1) / (float)(H_HR - 1);         // 255/1023

    const int y0min = (int)((float)i0 * scale);                        // floor, >= 0

    // ---- 1. stage lowres rows y0min-2 .. y0min+7 (both planes, 5 rounds)
    const int lrbase = c * (H_LR * W_LR);
    f4  stv[5];
    int soff[5];
    #pragma unroll
    for (int r = 0; r < 5; ++r) {
        const int  idx = r * 256 + t;              // 0..1279
        const bool isx = idx < NST * 64;           // first 640 = x plane
        const int  id2 = isx ? idx : idx - NST * 64;
        const int  lr  = id2 >> 6, q = id2 & 63;
        const int  gr  = y0min - 2 + lr;
        const float* src = isx ? xlr : ylr;
        f4 v = {0.f, 0.f, 0.f, 0.f};
        if (gr >= 0 && gr < H_LR) v = *(const f4*)(src + lrbase + gr * W_LR + q * 4);
        stv[r]  = v;
        soff[r] = (isx ? 0 : NST * W_LR) + lr * W_LR + q * 4;  // float offset
    }
    {
        float* base = (float*)lds;
        #pragma unroll
        for (int r = 0; r < 5; ++r) *(f4*)(base + soff[r]) = stv[r];
    }
    __syncthreads();                               // (1)

    // ---- 2. vertical rolling window sums, column t
    float vx[NST], vy[NST];
    #pragma unroll
    for (int l = 0; l < NST; ++l) { vx[l] = sx[l][t]; vy[l] = sy[l][t]; }
    __syncthreads();                               // (2) staging reads done; cs aliases

    float pxy[NST], pxx[NST];
    #pragma unroll
    for (int l = 0; l < NST; ++l) { pxy[l] = vx[l] * vy[l]; pxx[l] = vx[l] * vx[l]; }
    float s0 = 0.f, s1 = 0.f, s2 = 0.f, s3 = 0.f;
    #pragma unroll
    for (int l = 0; l < 5; ++l) { s0 += vx[l]; s1 += vy[l]; s2 += pxy[l]; s3 += pxx[l]; }
    #pragma unroll
    for (int rr = 0; rr < NAB; ++rr) {
        const f4 v = {s0, s1, s2, s3};
        *(f4*)&cs[rr][t + 2][0] = v;
        if (rr + 1 < NAB) {
            s0 += vx[rr + 5] - vx[rr];
            s1 += vy[rr + 5] - vy[rr];
            s2 += pxy[rr + 5] - pxy[rr];
            s3 += pxx[rr + 5] - pxx[rr];
        }
    }
    if (t < 2) {                                   // zero-pad columns
        const f4 z = {0.f, 0.f, 0.f, 0.f};
        #pragma unroll
        for (int rr = 0; rr < NAB; ++rr) {
            *(f4*)&cs[rr][t][0] = z;
            *(f4*)&cs[rr][t + W_LR + 2][0] = z;
        }
    }
    __syncthreads();                               // (3)

    // ---- 3. horizontal 5-tap + stats -> registers
    const int hcnt = min(t + RAD, W_LR - 1) - max(t - RAD, 0) + 1;
    float aa[NAB], bb[NAB];
    #pragma unroll
    for (int rr = 0; rr < NAB; ++rr) {
        f4 s = {0.f, 0.f, 0.f, 0.f};
        #pragma unroll
        for (int d = 0; d < 5; ++d) s += *(const f4*)&cs[rr][t + d][0];
        const int r  = y0min + rr;                 // may exceed 255: harmless (cnt>=2)
        const int v0 = max(r - RAD, 0), v1 = min(r + RAD, H_LR - 1);
        const float inv = 1.0f / (float)((v1 - v0 + 1) * hcnt);
        const float mx  = s.x * inv;
        const float my  = s.y * inv;
        const float cov = s.z * inv - mx * my;
        const float var = s.w * inv - mx * mx;
        aa[rr] = cov / (var + 1e-8f);
        bb[rr] = my - aa[rr] * mx;
    }
    __syncthreads();                               // (4) cs reads done; ab aliases

    #pragma unroll
    for (int rr = 0; rr < NAB; ++rr) ab[rr][t] = f2{aa[rr], bb[rr]};
    __syncthreads();                               // (5)

    // ---- 4. read back only columns {t-1, t, t+1} (clamped), all 6 rows
    const int cl = max(t - 1, 0), ch = min(t + 1, W_LR - 1);
    f2 A3[NAB][3];
    #pragma unroll
    for (int rr = 0; rr < NAB; ++rr) {
        A3[rr][0] = ab[rr][cl];
        A3[rr][1] = ab[rr][t];
        A3[rr][2] = ab[rr][ch];
    }

    // x-interp selectors per m (x0 in {t-1,t}, x1 in {t,t+1})
    float wxv[4];
    bool  lo[4], hi[4];
    #pragma unroll
    for (int m = 0; m < 4; ++m) {
        const int   j  = t * 4 + m;
        const float fx = (float)j * scale;
        const int   x0 = (int)fx;
        wxv[m] = fx - (float)x0;
        lo[m]  = (x0 < t);
        hi[m]  = (x0 == t) && (t < W_LR - 1);
    }

    // ---- 5. pipelined per-row: load k+PD | compute k | store k  (depth 8)
    const size_t hrbase = ((size_t)c << 20) + (size_t)i0 * W_HR + t * 4;
    f4 buf[PD];
    #pragma unroll
    for (int k = 0; k < PD; ++k)
        buf[k] = *(const f4*)(xhr + hrbase + (size_t)k * W_HR);

    #pragma unroll
    for (int k = 0; k < RPB; ++k) {                // fully unrolled: k&(PD-1) static
        const f4 xvk = buf[k & (PD - 1)];
        if (k + PD < RPB)
            buf[k & (PD - 1)] = *(const f4*)(xhr + hrbase + (size_t)(k + PD) * W_HR);

        // y-weights: at most 2 of 6 nonzero; branchless 6-term combine
        const float fy  = (float)(i0 + k) * scale;
        const int   yy0 = (int)fy;
        const float wy  = fy - (float)yy0;
        const int   l0  = yy0 - y0min;                       // 0..4
        const int   l1  = min(yy0 + 1, H_LR - 1) - y0min;    // 0..5
        f2 r0 = {0.f, 0.f}, r1 = {0.f, 0.f}, r2 = {0.f, 0.f};
        #pragma unroll
        for (int rr = 0; rr < NAB; ++rr) {
            const float w = (l0 == rr ? 1.f - wy : 0.f) + (l1 == rr ? wy : 0.f);
            r0 += w * A3[rr][0];
            r1 += w * A3[rr][1];
            r2 += w * A3[rr][2];
        }

        f4 ov;
        #pragma unroll
        for (int m = 0; m < 4; ++m) {
            const f2 pl = lo[m] ? r0 : r1;
            const f2 ph = hi[m] ? r2 : r1;
            const float a = pl.x * (1.f - wxv[m]) + ph.x * wxv[m];
            const float b = pl.y * (1.f - wxv[m]) + ph.y * wxv[m];
            ov[m] = a * xvk[m] + b;
        }
        __builtin_nontemporal_store(ov, (f4*)(out + hrbase + (size_t)k * W_HR));
    }
}

extern "C" void kernel_launch(void* const* d_in, const int* in_sizes, int n_in,
                              void* d_out, int out_size, void* d_ws, size_t ws_size,
                              hipStream_t stream) {
    const float* x_lr = (const float*)d_in[0];  // input_lowres  [8,3,256,256]
    const float* y_lr = (const float*)d_in[1];  // guide_lowres  [8,3,256,256]
    const float* x_hr = (const float*)d_in[2];  // input_highres [8,3,1024,1024]
    float* out = (float*)d_out;

    dim3 grid(H_HR / RPB, NC, 1);               // 64 x 24 = 1536 blocks (6/CU)
    fgf_fused<<<grid, 256, 0, stream>>>(x_lr, y_lr, x_hr, out);
}

// Round 9
// 41.100 us; speedup vs baseline: 1.0262x; 1.0262x over previous
//
#include <hip/hip_runtime.h>

// FastGuidedFilter, fully fused, 16 highres rows per block (1536 blocks = 6/CU).
// Phases 1-4 as round 7/8 (cheap, proven). Phase 5 changes:
//  - PLAIN stores (not nontemporal): out becomes L3-resident across graph
//    replays; x_hr(100MB)+out(100MB) < 256MB L3 -> HBM FETCH shrinks.
//  - asm-fenced depth-8 prefetch ring (R8's ring was collapsed by the
//    compiler: VGPR=60 proved the loads were sunk to point-of-use).
//  - shift-window y-combine: c0/c1 track rows l0,l0+1 (block-uniform switch,
//    <=4 taken branches per 16 rows) -> 6 pk-FMA instead of 18 + weight calc.
//  - packed f2 x-interp: (a,b) interpolated with 2 pk ops per pixel.

typedef float f4 __attribute__((ext_vector_type(4)));
typedef float f2 __attribute__((ext_vector_type(2)));

constexpr int H_LR = 256, W_LR = 256;
constexpr int H_HR = 1024, W_HR = 1024;
constexpr int NC   = 24;       // 8 * 3
constexpr int RAD  = 2;        // kernel_size 5
constexpr int RPB  = 16;       // highres rows per block
constexpr int NAB  = 6;        // A/b rows a 16-row group can touch
constexpr int NST  = 10;       // staged lowres rows (NAB + 2*RAD)
constexpr int CS_W = W_LR + 4; // zero-padded col-sum width
constexpr int PD   = 8;        // phase-5 prefetch depth

constexpr int LDS_BYTES = NAB * CS_W * 4 * 4;  // 24960 (largest aliased region)

__global__ void __launch_bounds__(256) fgf_fused(const float* __restrict__ xlr,
                                                 const float* __restrict__ ylr,
                                                 const float* __restrict__ xhr,
                                                 float* __restrict__ out) {
    __shared__ __align__(16) char lds[LDS_BYTES];
    auto sx = reinterpret_cast<float(*)[W_LR]>(lds);                   // [10][256]
    auto sy = reinterpret_cast<float(*)[W_LR]>(lds + NST * W_LR * 4);  // [10][256]
    auto cs = reinterpret_cast<float(*)[CS_W][4]>(lds);                // [6][260][4]
    auto ab = reinterpret_cast<f2(*)[W_LR]>(lds);                      // [6][256] f2

    const int c  = blockIdx.y;
    const int i0 = blockIdx.x * RPB;
    const int t  = (int)threadIdx.x;
    const float scale = (float)(H_LR - 1) / (float)(H_HR - 1);         // 255/1023

    const int y0min = (int)((float)i0 * scale);                        // floor, >= 0

    // ---- 1. stage lowres rows y0min-2 .. y0min+7 (both planes, 5 rounds)
    const int lrbase = c * (H_LR * W_LR);
    f4  stv[5];
    int soff[5];
    #pragma unroll
    for (int r = 0; r < 5; ++r) {
        const int  idx = r * 256 + t;              // 0..1279
        const bool isx = idx < NST * 64;           // first 640 = x plane
        const int  id2 = isx ? idx : idx - NST * 64;
        const int  lr  = id2 >> 6, q = id2 & 63;
        const int  gr  = y0min - 2 + lr;
        const float* src = isx ? xlr : ylr;
        f4 v = {0.f, 0.f, 0.f, 0.f};
        if (gr >= 0 && gr < H_LR) v = *(const f4*)(src + lrbase + gr * W_LR + q * 4);
        stv[r]  = v;
        soff[r] = (isx ? 0 : NST * W_LR) + lr * W_LR + q * 4;  // float offset
    }
    {
        float* base = (float*)lds;
        #pragma unroll
        for (int r = 0; r < 5; ++r) *(f4*)(base + soff[r]) = stv[r];
    }
    __syncthreads();                               // (1)

    // ---- 2. vertical rolling window sums, column t
    float vx[NST], vy[NST];
    #pragma unroll
    for (int l = 0; l < NST; ++l) { vx[l] = sx[l][t]; vy[l] = sy[l][t]; }
    __syncthreads();                               // (2) staging reads done; cs aliases

    float pxy[NST], pxx[NST];
    #pragma unroll
    for (int l = 0; l < NST; ++l) { pxy[l] = vx[l] * vy[l]; pxx[l] = vx[l] * vx[l]; }
    float s0 = 0.f, s1 = 0.f, s2 = 0.f, s3 = 0.f;
    #pragma unroll
    for (int l = 0; l < 5; ++l) { s0 += vx[l]; s1 += vy[l]; s2 += pxy[l]; s3 += pxx[l]; }
    #pragma unroll
    for (int rr = 0; rr < NAB; ++rr) {
        const f4 v = {s0, s1, s2, s3};
        *(f4*)&cs[rr][t + 2][0] = v;
        if (rr + 1 < NAB) {
            s0 += vx[rr + 5] - vx[rr];
            s1 += vy[rr + 5] - vy[rr];
            s2 += pxy[rr + 5] - pxy[rr];
            s3 += pxx[rr + 5] - pxx[rr];
        }
    }
    if (t < 2) {                                   // zero-pad columns
        const f4 z = {0.f, 0.f, 0.f, 0.f};
        #pragma unroll
        for (int rr = 0; rr < NAB; ++rr) {
            *(f4*)&cs[rr][t][0] = z;
            *(f4*)&cs[rr][t + W_LR + 2][0] = z;
        }
    }
    __syncthreads();                               // (3)

    // ---- 3. horizontal 5-tap + stats -> registers
    const int hcnt = min(t + RAD, W_LR - 1) - max(t - RAD, 0) + 1;
    float aa[NAB], bb[NAB];
    #pragma unroll
    for (int rr = 0; rr < NAB; ++rr) {
        f4 s = {0.f, 0.f, 0.f, 0.f};
        #pragma unroll
        for (int d = 0; d < 5; ++d) s += *(const f4*)&cs[rr][t + d][0];
        const int r  = y0min + rr;                 // may exceed 255: harmless (cnt>=2)
        const int v0 = max(r - RAD, 0), v1 = min(r + RAD, H_LR - 1);
        const float inv = 1.0f / (float)((v1 - v0 + 1) * hcnt);
        const float mx  = s.x * inv;
        const float my  = s.y * inv;
        const float cov = s.z * inv - mx * my;
        const float var = s.w * inv - mx * mx;
        aa[rr] = cov / (var + 1e-8f);
        bb[rr] = my - aa[rr] * mx;
    }
    __syncthreads();                               // (4) cs reads done; ab aliases

    #pragma unroll
    for (int rr = 0; rr < NAB; ++rr) ab[rr][t] = f2{aa[rr], bb[rr]};
    __syncthreads();                               // (5)

    // ---- 4. read back only columns {t-1, t, t+1} (clamped), all 6 rows
    const int cl = max(t - 1, 0), ch = min(t + 1, W_LR - 1);
    f2 A3[NAB][3];
    #pragma unroll
    for (int rr = 0; rr < NAB; ++rr) {
        A3[rr][0] = ab[rr][cl];
        A3[rr][1] = ab[rr][t];
        A3[rr][2] = ab[rr][ch];
    }

    // x-interp selectors per m (x0 in {t-1,t}, x1 in {t,t+1})
    float wxv[4], wx0v[4];
    bool  lo[4], hi[4];
    #pragma unroll
    for (int m = 0; m < 4; ++m) {
        const int   j  = t * 4 + m;
        const float fx = (float)j * scale;
        const int   x0 = (int)fx;
        wxv[m]  = fx - (float)x0;
        wx0v[m] = 1.f - wxv[m];
        lo[m]   = (x0 < t);
        hi[m]   = (x0 == t) && (t < W_LR - 1);
    }

    // ---- 5. asm-fenced depth-8 ring, plain stores, shift-window y-combine
    const size_t hrbase = ((size_t)c << 20) + (size_t)i0 * W_HR + t * 4;
    const float* srcp = xhr + hrbase;
    float*       dstp = out + hrbase;

    f4 buf[PD];
    #pragma unroll
    for (int k = 0; k < PD; ++k)
        buf[k] = *(const f4*)(srcp + (size_t)k * W_HR);
    asm volatile("" ::: "memory");                 // pin the 8 loads in flight

    f2 c0l = A3[0][0], c0c = A3[0][1], c0r = A3[0][2];
    f2 c1l = A3[1][0], c1c = A3[1][1], c1r = A3[1][2];
    int cur = 0;

    #pragma unroll
    for (int k = 0; k < RPB; ++k) {                // fully unrolled
        const f4 xvk = buf[k & (PD - 1)];

        const float fy  = (float)(i0 + k) * scale;
        const int   yy0 = (int)fy;
        const int   l0  = yy0 - y0min;             // 0..4, block-uniform
        if (l0 != cur) {                           // uniform branch, +1 steps
            c0l = c1l; c0c = c1c; c0r = c1r;
            const int nxt = (l0 + 1 < NAB) ? l0 + 1 : NAB - 1;
            switch (nxt) {
                case 2:  c1l = A3[2][0]; c1c = A3[2][1]; c1r = A3[2][2]; break;
                case 3:  c1l = A3[3][0]; c1c = A3[3][1]; c1r = A3[3][2]; break;
                case 4:  c1l = A3[4][0]; c1c = A3[4][1]; c1r = A3[4][2]; break;
                default: c1l = A3[5][0]; c1c = A3[5][1]; c1r = A3[5][2]; break;
            }
            cur = l0;
        }
        // clamp row: when yy0==255, reference's y1==y0 -> weight collapses
        const float wyk = (yy0 < H_LR - 1) ? (fy - (float)yy0) : 0.f;
        const float wy0 = 1.f - wyk;
        const f2 r0 = wy0 * c0l + wyk * c1l;
        const f2 r1 = wy0 * c0c + wyk * c1c;
        const f2 r2 = wy0 * c0r + wyk * c1r;

        f4 ov;
        #pragma unroll
        for (int m = 0; m < 4; ++m) {
            const f2 pl  = lo[m] ? r0 : r1;
            const f2 ph  = hi[m] ? r2 : r1;
            const f2 abv = wx0v[m] * pl + wxv[m] * ph;   // packed (a,b)
            ov[m] = abv.x * xvk[m] + abv.y;
        }
        *(f4*)(dstp + (size_t)k * W_HR) = ov;      // cached store (L3-resident)

        if (k + PD < RPB) {
            buf[k & (PD - 1)] = *(const f4*)(srcp + (size_t)(k + PD) * W_HR);
            asm volatile("" ::: "memory");         // keep ring depth real
        }
    }
}

extern "C" void kernel_launch(void* const* d_in, const int* in_sizes, int n_in,
                              void* d_out, int out_size, void* d_ws, size_t ws_size,
                              hipStream_t stream) {
    const float* x_lr = (const float*)d_in[0];  // input_lowres  [8,3,256,256]
    const float* y_lr = (const float*)d_in[1];  // guide_lowres  [8,3,256,256]
    const float* x_hr = (const float*)d_in[2];  // input_highres [8,3,1024,1024]
    float* out = (float*)d_out;

    dim3 grid(H_HR / RPB, NC, 1);               // 64 x 24 = 1536 blocks (6/CU)
    fgf_fused<<<grid, 256, 0, stream>>>(x_lr, y_lr, x_hr, out);
}